// Round 1
// baseline (4041.402 us; speedup 1.0000x reference)
//
#include <hip/hip_runtime.h>
#include <cstdint>
#include <cstddef>

#define NN 100000
#define NE 1600000

// pre-buffer layout (float offsets)
#define PRE_GLOB 0      // 64   glob_lat
#define PRE_WC   64     // 192  Wcomb (3x64): folded w_ee@ew1_edge
#define PRE_CVEC 256    // 64   eb1 + b_ee@ew1_edge + glob@ew1_glob
#define PRE_CN   320    // 64   b_en + t(0)*sum(w_en[0:4])
#define PRE_NGV  384    // 64   nb1 + glob@nw1_glob
#define PRE_WSR  448    // 4096 ew1_send+ew1_recv
#define PRE_NSR  4544   // 4096 nw1_send+nw1_recv

__device__ __forceinline__ float asinhf_fast(float x){
    float ax = fabsf(x);
    float r = __logf(ax + sqrtf(fmaf(ax, ax, 1.0f)));
    return copysignf(r, x);
}
__device__ __forceinline__ float gelu_f(float x){
    // jax.nn.gelu approximate=True: 0.5x(1+tanh(sqrt(2/pi)(x+0.044715x^3)))
    float x3 = x * x * x;
    float z = 0.7978845608028654f * fmaf(0.044715f, x3, x);
    float e = __expf(2.0f * z);
    float th = 1.0f - 2.0f / (e + 1.0f);
    return 0.5f * x * (1.0f + th);
}
__device__ __forceinline__ unsigned fkey(float f){
    unsigned u = __float_as_uint(f);
    return (u & 0x80000000u) ? ~u : (u | 0x80000000u);
}
__device__ __forceinline__ float funkey(unsigned k){
    unsigned u = (k & 0x80000000u) ? (k ^ 0x80000000u) : ~k;
    return __uint_as_float(u);
}
__device__ __forceinline__ void atomAddF(float* p, float v){
#if defined(__HIP_DEVICE_COMPILE__)
    unsafeAtomicAdd(p, v);   // hardware global_atomic_add_f32, not CAS loop
#else
    atomicAdd(p, v);
#endif
}
__device__ __forceinline__ void fma16(float acc[4][4], float4 a, float4 b){
    float av[4] = {a.x, a.y, a.z, a.w};
    float bv[4] = {b.x, b.y, b.z, b.w};
#pragma unroll
    for (int i = 0; i < 4; ++i)
#pragma unroll
        for (int c = 0; c < 4; ++c)
            acc[i][c] = fmaf(av[i], bv[c], acc[i][c]);
}

// ---------------- precompute (1 block x 64 threads) ----------------
__global__ void k_pre(const float* an, const float* w_en, const float* b_en,
                      const float* ae, const float* w_ee, const float* b_ee,
                      const float* ag, const float* w_eg, const float* b_eg,
                      const float* ew1, const float* eb1,
                      const float* nw1, const float* nb1, float* pre)
{
    __shared__ float gls[64];
    int t = threadIdx.x;
    float g0 = asinhf_fast(100000.0f);
    float g1 = asinhf_fast(1600000.0f);
    float tg0 = fmaf(ag[0], asinhf_fast(fmaf(ag[1], g0, ag[2])), ag[3]);
    float tg1 = fmaf(ag[0], asinhf_fast(fmaf(ag[1], g1, ag[2])), ag[3]);
    float gl = fmaf(tg0, w_eg[t], fmaf(tg1, w_eg[64 + t], b_eg[t]));
    pre[PRE_GLOB + t] = gl;
    gls[t] = gl;
    __syncthreads();
    for (int i = 0; i < 3; ++i){
        float s = 0.f;
        for (int j = 0; j < 64; ++j) s = fmaf(w_ee[i * 64 + j], ew1[j * 64 + t], s);
        pre[PRE_WC + i * 64 + t] = s;
    }
    {
        float s = eb1[t];
        for (int j = 0; j < 64; ++j) s = fmaf(b_ee[j], ew1[j * 64 + t], s);
        for (int j = 0; j < 64; ++j) s = fmaf(gls[j], ew1[(192 + j) * 64 + t], s);
        pre[PRE_CVEC + t] = s;
    }
    {
        float tz = fmaf(an[0], asinhf_fast(an[2]), an[3]);   // asinh_layer(0)
        pre[PRE_CN + t] = fmaf(tz, w_en[t] + w_en[64 + t] + w_en[128 + t] + w_en[192 + t], b_en[t]);
    }
    {
        float s = nb1[t];
        for (int j = 0; j < 64; ++j) s = fmaf(gls[j], nw1[(192 + j) * 64 + t], s);
        pre[PRE_NGV + t] = s;
    }
    for (int j = 0; j < 64; ++j){
        pre[PRE_WSR + j * 64 + t] = ew1[(64 + j) * 64 + t] + ew1[(128 + j) * 64 + t];
        pre[PRE_NSR + j * 64 + t] = nw1[(64 + j) * 64 + t] + nw1[(128 + j) * 64 + t];
    }
}

// ---------------- node embedding: lat = asinh_layer(nodes)@w_en+b_en ----------------
__global__ __launch_bounds__(256) void k_embed(const float* nodes, const float* an,
                                               const float* w_en, const float* pre, float* lat)
{
    int t = threadIdx.x;
    int k = t & 63;
    int n = blockIdx.x * 4 + (t >> 6);
    float pa = an[0], pb = an[1], pc = an[2], pd = an[3];
    const float* row = nodes + (size_t)n * 7;
    float t4 = fmaf(pa, asinhf_fast(fmaf(pb, row[4], pc)), pd);
    float t5 = fmaf(pa, asinhf_fast(fmaf(pb, row[5], pc)), pd);
    float t6 = fmaf(pa, asinhf_fast(fmaf(pb, row[6], pc)), pd);
    float v = pre[PRE_CN + k];
    v = fmaf(t4, w_en[4 * 64 + k], v);
    v = fmaf(t5, w_en[5 * 64 + k], v);
    v = fmaf(t6, w_en[6 * 64 + k], v);
    lat[(size_t)n * 64 + k] = v;
}

// ---------------- nproj = lat @ (ew1_send + ew1_recv) ----------------
__global__ __launch_bounds__(256) void k_nproj(const float* lat, const float* pre, float* nproj)
{
    __shared__ float AT[64][68];
    int t = threadIdx.x;
    int base = blockIdx.x * 64;
    int cnt = NN - base; if (cnt > 64) cnt = 64;
#pragma unroll
    for (int it = 0; it < 4; ++it){
        int flat = it * 1024 + t * 4;
        int n = flat >> 6, j = flat & 63;
        float4 v = make_float4(0.f, 0.f, 0.f, 0.f);
        if (n < cnt) v = *(const float4*)(lat + (size_t)(base + n) * 64 + j);
        AT[j + 0][n] = v.x; AT[j + 1][n] = v.y; AT[j + 2][n] = v.z; AT[j + 3][n] = v.w;
    }
    __syncthreads();
    int e0 = (t & 15) * 4, k0 = (t >> 4) * 4;
    float acc[4][4];
#pragma unroll
    for (int i = 0; i < 4; ++i)
#pragma unroll
        for (int c = 0; c < 4; ++c) acc[i][c] = 0.f;
    const float* Wsr = pre + PRE_WSR;
#pragma unroll 4
    for (int j = 0; j < 64; ++j){
        float4 a = *(const float4*)&AT[j][e0];
        float4 b = *(const float4*)(Wsr + j * 64 + k0);
        fma16(acc, a, b);
    }
#pragma unroll
    for (int i = 0; i < 4; ++i){
        int n = e0 + i;
        if (n < cnt){
            float4 o = make_float4(acc[i][0], acc[i][1], acc[i][2], acc[i][3]);
            *(float4*)(nproj + (size_t)(base + n) * 64 + k0) = o;
        }
    }
}

// ---------------- edge MLP + segment_sum scatter + edge stats ----------------
__global__ __launch_bounds__(256) void k_edge(const float* edges, const int* senders,
                                              const float* nproj, const float* pre,
                                              const float* ae, const float* ew2, const float* eb2,
                                              float* sent, float* esum, float* esumsq, unsigned* emax)
{
    __shared__ float hT[64][68];
    __shared__ int sArr[64];
    int t = threadIdx.x;
    int e = t & 63, kq = t >> 6;
    int eg = blockIdx.x * 64 + e;
    int s = senders[eg];
    if (kq == 0) sArr[e] = s;
    float pa = ae[0], pb = ae[1], pc = ae[2], pd = ae[3];
    const float* erow = edges + (size_t)eg * 3;
    float t0 = fmaf(pa, asinhf_fast(fmaf(pb, erow[0], pc)), pd);
    float t1 = fmaf(pa, asinhf_fast(fmaf(pb, erow[1], pc)), pd);
    float t2 = fmaf(pa, asinhf_fast(fmaf(pb, erow[2], pc)), pd);
    int j0 = kq * 16;
    const float* np = nproj + (size_t)s * 64 + j0;
    float npv[16];
#pragma unroll
    for (int q = 0; q < 4; ++q){
        float4 v = *(const float4*)(np + q * 4);
        npv[q * 4 + 0] = v.x; npv[q * 4 + 1] = v.y; npv[q * 4 + 2] = v.z; npv[q * 4 + 3] = v.w;
    }
    const float* Wc = pre + PRE_WC;
    const float* cvec = pre + PRE_CVEC;
#pragma unroll
    for (int jj = 0; jj < 16; ++jj){
        int j = j0 + jj;
        float hp = cvec[j] + npv[jj];
        hp = fmaf(t0, Wc[j], hp);
        hp = fmaf(t1, Wc[64 + j], hp);
        hp = fmaf(t2, Wc[128 + j], hp);
        hT[j][e] = gelu_f(hp);
    }
    __syncthreads();
    int e0 = (t & 15) * 4, k0 = (t >> 4) * 4;
    float acc[4][4];
    {
        float4 bb = *(const float4*)(eb2 + k0);
#pragma unroll
        for (int i = 0; i < 4; ++i){ acc[i][0] = bb.x; acc[i][1] = bb.y; acc[i][2] = bb.z; acc[i][3] = bb.w; }
    }
#pragma unroll 4
    for (int j = 0; j < 64; ++j){
        float4 a = *(const float4*)&hT[j][e0];
        float4 b = *(const float4*)(ew2 + j * 64 + k0);
        fma16(acc, a, b);
    }
    // scatter: sent[s] += out  (segment_sum)
#pragma unroll
    for (int i = 0; i < 4; ++i){
        int sv = sArr[e0 + i];
        float* dst = sent + (size_t)sv * 64 + k0;
        atomAddF(dst + 0, acc[i][0]);
        atomAddF(dst + 1, acc[i][1]);
        atomAddF(dst + 2, acc[i][2]);
        atomAddF(dst + 3, acc[i][3]);
    }
    // fused stats over raw edge outputs
    float ps[4], pq[4], pm[4];
#pragma unroll
    for (int c = 0; c < 4; ++c){
        float s0 = acc[0][c], s1 = acc[1][c], s2 = acc[2][c], s3 = acc[3][c];
        ps[c] = (s0 + s1) + (s2 + s3);
        pq[c] = fmaf(s0, s0, fmaf(s1, s1, fmaf(s2, s2, s3 * s3)));
        pm[c] = fmaxf(fmaxf(s0, s1), fmaxf(s2, s3));
    }
#pragma unroll
    for (int m = 1; m < 16; m <<= 1){
#pragma unroll
        for (int c = 0; c < 4; ++c){
            ps[c] += __shfl_xor(ps[c], m);
            pq[c] += __shfl_xor(pq[c], m);
            pm[c] = fmaxf(pm[c], __shfl_xor(pm[c], m));
        }
    }
    if ((t & 15) == 0){
#pragma unroll
        for (int c = 0; c < 4; ++c){
            atomAddF(esum + k0 + c, ps[c]);
            atomAddF(esumsq + k0 + c, pq[c]);
            atomicMax(emax + k0 + c, fkey(pm[c]));
        }
    }
}

// ---------------- node MLP + node stats ----------------
__global__ __launch_bounds__(256) void k_node(const float* lat, const float* sent, const float* pre,
                                              const float* nw1, const float* nw2, const float* nb2,
                                              float* nsum, float* nsumsq, unsigned* nmax)
{
    __shared__ float ATl[64][68];
    __shared__ float ATs[64][68];
    __shared__ float h2T[64][68];
    int t = threadIdx.x;
    int base = blockIdx.x * 64;
    int cnt = NN - base; if (cnt > 64) cnt = 64;
#pragma unroll
    for (int it = 0; it < 4; ++it){
        int flat = it * 1024 + t * 4;
        int n = flat >> 6, j = flat & 63;
        float4 v = make_float4(0.f, 0.f, 0.f, 0.f);
        float4 w = make_float4(0.f, 0.f, 0.f, 0.f);
        if (n < cnt){
            v = *(const float4*)(lat + (size_t)(base + n) * 64 + j);
            w = *(const float4*)(sent + (size_t)(base + n) * 64 + j);
        }
        ATl[j + 0][n] = v.x; ATl[j + 1][n] = v.y; ATl[j + 2][n] = v.z; ATl[j + 3][n] = v.w;
        ATs[j + 0][n] = w.x; ATs[j + 1][n] = w.y; ATs[j + 2][n] = w.z; ATs[j + 3][n] = w.w;
    }
    __syncthreads();
    int e0 = (t & 15) * 4, k0 = (t >> 4) * 4;
    const float* Nsr = pre + PRE_NSR;
    float acc[4][4];
    {
        float4 g = *(const float4*)(pre + PRE_NGV + k0);
#pragma unroll
        for (int i = 0; i < 4; ++i){ acc[i][0] = g.x; acc[i][1] = g.y; acc[i][2] = g.z; acc[i][3] = g.w; }
    }
#pragma unroll 2
    for (int j = 0; j < 64; ++j){
        float4 a = *(const float4*)&ATl[j][e0];
        float4 b = *(const float4*)(nw1 + j * 64 + k0);
        fma16(acc, a, b);
        float4 a2 = *(const float4*)&ATs[j][e0];
        float4 b2 = *(const float4*)(Nsr + j * 64 + k0);
        fma16(acc, a2, b2);
    }
#pragma unroll
    for (int i = 0; i < 4; ++i)
#pragma unroll
        for (int c = 0; c < 4; ++c)
            h2T[k0 + c][e0 + i] = gelu_f(acc[i][c]);
    __syncthreads();
    float acc2[4][4];
    {
        float4 bb = *(const float4*)(nb2 + k0);
#pragma unroll
        for (int i = 0; i < 4; ++i){ acc2[i][0] = bb.x; acc2[i][1] = bb.y; acc2[i][2] = bb.z; acc2[i][3] = bb.w; }
    }
#pragma unroll 4
    for (int j = 0; j < 64; ++j){
        float4 a = *(const float4*)&h2T[j][e0];
        float4 b = *(const float4*)(nw2 + j * 64 + k0);
        fma16(acc2, a, b);
    }
    float ps[4] = {0.f, 0.f, 0.f, 0.f}, pq[4] = {0.f, 0.f, 0.f, 0.f}, pm[4];
#pragma unroll
    for (int c = 0; c < 4; ++c) pm[c] = -INFINITY;
#pragma unroll
    for (int i = 0; i < 4; ++i){
        if (e0 + i < cnt){
#pragma unroll
            for (int c = 0; c < 4; ++c){
                float v = acc2[i][c];
                ps[c] += v;
                pq[c] = fmaf(v, v, pq[c]);
                pm[c] = fmaxf(pm[c], v);
            }
        }
    }
#pragma unroll
    for (int m = 1; m < 16; m <<= 1){
#pragma unroll
        for (int c = 0; c < 4; ++c){
            ps[c] += __shfl_xor(ps[c], m);
            pq[c] += __shfl_xor(pq[c], m);
            pm[c] = fmaxf(pm[c], __shfl_xor(pm[c], m));
        }
    }
    if ((t & 15) == 0){
#pragma unroll
        for (int c = 0; c < 4; ++c){
            atomAddF(nsum + k0 + c, ps[c]);
            atomAddF(nsumsq + k0 + c, pq[c]);
            atomicMax(nmax + k0 + c, fkey(pm[c]));
        }
    }
}

// ---------------- global head (1 block x 64) ----------------
__global__ void k_final(const float* pre,
                        const float* nsum, const float* nsumsq, const unsigned* nmax,
                        const float* esum, const float* esumsq, const unsigned* emax,
                        const float* gw1, const float* gb1, const float* gw2, const float* gb2,
                        const float* gw3, const float* gb3, float* out)
{
    __shared__ float gin[576];
    __shared__ float l1s[64];
    __shared__ float l2s[64];
    int t = threadIdx.x;
    {
        float s = nsum[t];
        float mean = s / 100000.0f;
        float var = nsumsq[t] / 100000.0f - mean * mean;
        gin[t] = asinhf_fast(s);
        gin[64 + t] = asinhf_fast(mean);
        gin[128 + t] = asinhf_fast(var);
        gin[192 + t] = asinhf_fast(funkey(nmax[t]));
        float se = esum[t];
        float meane = se / 1600000.0f;
        float vare = esumsq[t] / 1600000.0f - meane * meane;
        gin[256 + t] = asinhf_fast(se);
        gin[320 + t] = asinhf_fast(meane);
        gin[384 + t] = asinhf_fast(vare);
        gin[448 + t] = asinhf_fast(funkey(emax[t]));
        gin[512 + t] = pre[PRE_GLOB + t];
    }
    __syncthreads();
    float a1 = gb1[t];
    for (int j = 0; j < 576; ++j) a1 = fmaf(gin[j], gw1[j * 64 + t], a1);
    l1s[t] = gelu_f(a1);
    __syncthreads();
    float a2 = gb2[t];
    for (int j = 0; j < 64; ++j) a2 = fmaf(l1s[j], gw2[j * 64 + t], a2);
    l2s[t] = gelu_f(a2);
    __syncthreads();
    if (t < 2){
        float s = gb3[t];
        for (int j = 0; j < 64; ++j) s = fmaf(l2s[j], gw3[j * 2 + t], s);
        out[t] = s;
    }
}

extern "C" void kernel_launch(void* const* d_in, const int* in_sizes, int n_in,
                              void* d_out, int out_size, void* d_ws, size_t ws_size,
                              hipStream_t stream)
{
    const float* nodes  = (const float*)d_in[0];
    const float* edges  = (const float*)d_in[1];
    const int*   senders= (const int*)d_in[2];
    const float* an  = (const float*)d_in[3];
    const float* w_en= (const float*)d_in[4];
    const float* b_en= (const float*)d_in[5];
    const float* ae  = (const float*)d_in[6];
    const float* w_ee= (const float*)d_in[7];
    const float* b_ee= (const float*)d_in[8];
    const float* ag  = (const float*)d_in[9];
    const float* w_eg= (const float*)d_in[10];
    const float* b_eg= (const float*)d_in[11];
    const float* ew1 = (const float*)d_in[12];
    const float* eb1 = (const float*)d_in[13];
    const float* ew2 = (const float*)d_in[14];
    const float* eb2 = (const float*)d_in[15];
    const float* nw1 = (const float*)d_in[16];
    const float* nb1 = (const float*)d_in[17];
    const float* nw2 = (const float*)d_in[18];
    const float* nb2 = (const float*)d_in[19];
    const float* gw1 = (const float*)d_in[20];
    const float* gb1 = (const float*)d_in[21];
    const float* gw2 = (const float*)d_in[22];
    const float* gb2 = (const float*)d_in[23];
    const float* gw3 = (const float*)d_in[24];
    const float* gb3 = (const float*)d_in[25];

    char* ws = (char*)d_ws;
    float* lat   = (float*)(ws);                         // 25.6 MB
    float* nproj = (float*)(ws + 25600000);              // 25.6 MB
    float* sent  = (float*)(ws + 51200000);              // 25.6 MB
    float* pre   = (float*)(ws + 76800000);              // 34.6 KB (64 KB reserved)
    float* stats = (float*)(ws + 76800000 + 65536);      // 1.5 KB
    float* esum = stats;            float* esumsq = stats + 64;  unsigned* emax = (unsigned*)(stats + 128);
    float* nsum = stats + 192;      float* nsumsq = stats + 256; unsigned* nmax = (unsigned*)(stats + 320);

    hipMemsetAsync(sent, 0, (size_t)NN * 64 * sizeof(float), stream);
    hipMemsetAsync(stats, 0, 384 * sizeof(float), stream);

    hipLaunchKernelGGL(k_pre, dim3(1), dim3(64), 0, stream,
                       an, w_en, b_en, ae, w_ee, b_ee, ag, w_eg, b_eg, ew1, eb1, nw1, nb1, pre);
    hipLaunchKernelGGL(k_embed, dim3(NN / 4), dim3(256), 0, stream, nodes, an, w_en, pre, lat);
    hipLaunchKernelGGL(k_nproj, dim3((NN + 63) / 64), dim3(256), 0, stream, lat, pre, nproj);
    hipLaunchKernelGGL(k_edge, dim3(NE / 64), dim3(256), 0, stream,
                       edges, senders, nproj, pre, ae, ew2, eb2, sent, esum, esumsq, emax);
    hipLaunchKernelGGL(k_node, dim3((NN + 63) / 64), dim3(256), 0, stream,
                       lat, sent, pre, nw1, nw2, nb2, nsum, nsumsq, nmax);
    hipLaunchKernelGGL(k_final, dim3(1), dim3(64), 0, stream,
                       pre, nsum, nsumsq, nmax, esum, esumsq, emax,
                       gw1, gb1, gw2, gb2, gw3, gb3, (float*)d_out);
}

// Round 2
// 972.084 us; speedup vs baseline: 4.1575x; 4.1575x over previous
//
#include <hip/hip_runtime.h>
#include <cstdint>
#include <cstddef>

#define NN 100000
#define NE 1600000
#define NSLICE 16

// pre-buffer layout (float offsets)
#define PRE_GLOB 0      // 64   glob_lat
#define PRE_WC   64     // 192  Wcomb (3x64): folded w_ee@ew1_edge
#define PRE_CVEC 256    // 64   eb1 + b_ee@ew1_edge + glob@ew1_glob
#define PRE_CN   320    // 64   b_en + t(0)*sum(w_en[0:4])
#define PRE_NGV  384    // 64   nb1 + glob@nw1_glob
#define PRE_WSR  448    // 4096 ew1_send+ew1_recv
#define PRE_NSR  4544   // 4096 nw1_send+nw1_recv

__device__ __forceinline__ float asinhf_fast(float x){
    float ax = fabsf(x);
    float r = __logf(ax + sqrtf(fmaf(ax, ax, 1.0f)));
    return copysignf(r, x);
}
__device__ __forceinline__ float gelu_f(float x){
    float x3 = x * x * x;
    float z = 0.7978845608028654f * fmaf(0.044715f, x3, x);
    float e = __expf(2.0f * z);
    float th = 1.0f - 2.0f / (e + 1.0f);
    return 0.5f * x * (1.0f + th);
}
__device__ __forceinline__ unsigned fkey(float f){
    unsigned u = __float_as_uint(f);
    return (u & 0x80000000u) ? ~u : (u | 0x80000000u);
}
__device__ __forceinline__ float funkey(unsigned k){
    unsigned u = (k & 0x80000000u) ? (k ^ 0x80000000u) : ~k;
    return __uint_as_float(u);
}
__device__ __forceinline__ void atomAddF(float* p, float v){
#if defined(__HIP_DEVICE_COMPILE__)
    unsafeAtomicAdd(p, v);
#else
    atomicAdd(p, v);
#endif
}
__device__ __forceinline__ void fma16(float acc[4][4], float4 a, float4 b){
    float av[4] = {a.x, a.y, a.z, a.w};
    float bv[4] = {b.x, b.y, b.z, b.w};
#pragma unroll
    for (int i = 0; i < 4; ++i)
#pragma unroll
        for (int c = 0; c < 4; ++c)
            acc[i][c] = fmaf(av[i], bv[c], acc[i][c]);
}

// ---------------- precompute (1 block x 64 threads) ----------------
__global__ void k_pre(const float* an, const float* w_en, const float* b_en,
                      const float* ae, const float* w_ee, const float* b_ee,
                      const float* ag, const float* w_eg, const float* b_eg,
                      const float* ew1, const float* eb1,
                      const float* nw1, const float* nb1, float* pre)
{
    __shared__ float gls[64];
    int t = threadIdx.x;
    float g0 = asinhf_fast(100000.0f);
    float g1 = asinhf_fast(1600000.0f);
    float tg0 = fmaf(ag[0], asinhf_fast(fmaf(ag[1], g0, ag[2])), ag[3]);
    float tg1 = fmaf(ag[0], asinhf_fast(fmaf(ag[1], g1, ag[2])), ag[3]);
    float gl = fmaf(tg0, w_eg[t], fmaf(tg1, w_eg[64 + t], b_eg[t]));
    pre[PRE_GLOB + t] = gl;
    gls[t] = gl;
    __syncthreads();
    for (int i = 0; i < 3; ++i){
        float s = 0.f;
        for (int j = 0; j < 64; ++j) s = fmaf(w_ee[i * 64 + j], ew1[j * 64 + t], s);
        pre[PRE_WC + i * 64 + t] = s;
    }
    {
        float s = eb1[t];
        for (int j = 0; j < 64; ++j) s = fmaf(b_ee[j], ew1[j * 64 + t], s);
        for (int j = 0; j < 64; ++j) s = fmaf(gls[j], ew1[(192 + j) * 64 + t], s);
        pre[PRE_CVEC + t] = s;
    }
    {
        float tz = fmaf(an[0], asinhf_fast(an[2]), an[3]);
        pre[PRE_CN + t] = fmaf(tz, w_en[t] + w_en[64 + t] + w_en[128 + t] + w_en[192 + t], b_en[t]);
    }
    {
        float s = nb1[t];
        for (int j = 0; j < 64; ++j) s = fmaf(gls[j], nw1[(192 + j) * 64 + t], s);
        pre[PRE_NGV + t] = s;
    }
    for (int j = 0; j < 64; ++j){
        pre[PRE_WSR + j * 64 + t] = ew1[(64 + j) * 64 + t] + ew1[(128 + j) * 64 + t];
        pre[PRE_NSR + j * 64 + t] = nw1[(64 + j) * 64 + t] + nw1[(128 + j) * 64 + t];
    }
}

// ---------------- node embedding ----------------
__global__ __launch_bounds__(256) void k_embed(const float* nodes, const float* an,
                                               const float* w_en, const float* pre, float* lat)
{
    int t = threadIdx.x;
    int k = t & 63;
    int n = blockIdx.x * 4 + (t >> 6);
    float pa = an[0], pb = an[1], pc = an[2], pd = an[3];
    const float* row = nodes + (size_t)n * 7;
    float t4 = fmaf(pa, asinhf_fast(fmaf(pb, row[4], pc)), pd);
    float t5 = fmaf(pa, asinhf_fast(fmaf(pb, row[5], pc)), pd);
    float t6 = fmaf(pa, asinhf_fast(fmaf(pb, row[6], pc)), pd);
    float v = pre[PRE_CN + k];
    v = fmaf(t4, w_en[4 * 64 + k], v);
    v = fmaf(t5, w_en[5 * 64 + k], v);
    v = fmaf(t6, w_en[6 * 64 + k], v);
    lat[(size_t)n * 64 + k] = v;
}

// ---------------- nproj = lat @ (ew1_send + ew1_recv) ----------------
__global__ __launch_bounds__(256) void k_nproj(const float* lat, const float* pre, float* nproj)
{
    __shared__ float AT[64][68];
    int t = threadIdx.x;
    int base = blockIdx.x * 64;
    int cnt = NN - base; if (cnt > 64) cnt = 64;
#pragma unroll
    for (int it = 0; it < 4; ++it){
        int flat = it * 1024 + t * 4;
        int n = flat >> 6, j = flat & 63;
        float4 v = make_float4(0.f, 0.f, 0.f, 0.f);
        if (n < cnt) v = *(const float4*)(lat + (size_t)(base + n) * 64 + j);
        AT[j + 0][n] = v.x; AT[j + 1][n] = v.y; AT[j + 2][n] = v.z; AT[j + 3][n] = v.w;
    }
    __syncthreads();
    int e0 = (t & 15) * 4, k0 = (t >> 4) * 4;
    float acc[4][4];
#pragma unroll
    for (int i = 0; i < 4; ++i)
#pragma unroll
        for (int c = 0; c < 4; ++c) acc[i][c] = 0.f;
    const float* Wsr = pre + PRE_WSR;
#pragma unroll 4
    for (int j = 0; j < 64; ++j){
        float4 a = *(const float4*)&AT[j][e0];
        float4 b = *(const float4*)(Wsr + j * 64 + k0);
        fma16(acc, a, b);
    }
#pragma unroll
    for (int i = 0; i < 4; ++i){
        int n = e0 + i;
        if (n < cnt){
            float4 o = make_float4(acc[i][0], acc[i][1], acc[i][2], acc[i][3]);
            *(float4*)(nproj + (size_t)(base + n) * 64 + k0) = o;
        }
    }
}

// ---------------- counting sort: histogram ----------------
__global__ __launch_bounds__(256) void k_hist(const int* senders, int* counts)
{
    int i = blockIdx.x * 256 + threadIdx.x;
    atomicAdd(&counts[senders[i]], 1);
}

// ---------------- exclusive scan -> cursor (1 block x 1024) ----------------
__global__ __launch_bounds__(1024) void k_scan(const int* counts, int* cursor)
{
    __shared__ int part[1024];
    int t = threadIdx.x;
    const int CH = (NN + 1023) / 1024;
    int beg = t * CH; if (beg > NN) beg = NN;
    int end = beg + CH; if (end > NN) end = NN;
    int s = 0;
    for (int i = beg; i < end; ++i) s += counts[i];
    part[t] = s;
    __syncthreads();
    for (int off = 1; off < 1024; off <<= 1){
        int v = (t >= off) ? part[t - off] : 0;
        __syncthreads();
        if (t >= off) part[t] += v;
        __syncthreads();
    }
    int pref = (t == 0) ? 0 : part[t - 1];
    for (int i = beg; i < end; ++i){ cursor[i] = pref; pref += counts[i]; }
}

// ---------------- permute edge inputs into CSR order ----------------
__global__ __launch_bounds__(256) void k_assign(const float* edges, const int* senders,
                                                int* cursor, float4* eperm)
{
    int i = blockIdx.x * 256 + threadIdx.x;
    int s = senders[i];
    int slot = atomicAdd(&cursor[s], 1);
    const float* er = edges + (size_t)i * 3;
    eperm[slot] = make_float4(er[0], er[1], er[2], __int_as_float(s));
}

// ---------------- edge MLP, sorted: per-block segment sum ----------------
__global__ __launch_bounds__(256) void k_edge_sorted(const float4* eperm, const float* nproj,
                                                     const float* pre, const float* ae,
                                                     const float* ew2, const float* eb2,
                                                     float* sent, float* epart)
{
    __shared__ float hT[64][68];
    __shared__ float oS[64][65];
    __shared__ int sArr[64];
    int t = threadIdx.x;
    int e = t & 63, kq = t >> 6;
    float4 ed = eperm[blockIdx.x * 64 + e];
    int s = __float_as_int(ed.w);
    if (kq == 0) sArr[e] = s;
    float pa = ae[0], pb = ae[1], pc = ae[2], pd = ae[3];
    float t0 = fmaf(pa, asinhf_fast(fmaf(pb, ed.x, pc)), pd);
    float t1 = fmaf(pa, asinhf_fast(fmaf(pb, ed.y, pc)), pd);
    float t2 = fmaf(pa, asinhf_fast(fmaf(pb, ed.z, pc)), pd);
    int j0 = kq * 16;
    const float* np = nproj + (size_t)s * 64 + j0;
    float npv[16];
#pragma unroll
    for (int q = 0; q < 4; ++q){
        float4 v = *(const float4*)(np + q * 4);
        npv[q * 4 + 0] = v.x; npv[q * 4 + 1] = v.y; npv[q * 4 + 2] = v.z; npv[q * 4 + 3] = v.w;
    }
    const float* Wc = pre + PRE_WC;
    const float* cvec = pre + PRE_CVEC;
#pragma unroll
    for (int jj = 0; jj < 16; ++jj){
        int j = j0 + jj;
        float hp = cvec[j] + npv[jj];
        hp = fmaf(t0, Wc[j], hp);
        hp = fmaf(t1, Wc[64 + j], hp);
        hp = fmaf(t2, Wc[128 + j], hp);
        hT[j][e] = gelu_f(hp);
    }
    __syncthreads();
    int e0 = (t & 15) * 4, k0 = (t >> 4) * 4;
    float acc[4][4];
    {
        float4 bb = *(const float4*)(eb2 + k0);
#pragma unroll
        for (int i = 0; i < 4; ++i){ acc[i][0] = bb.x; acc[i][1] = bb.y; acc[i][2] = bb.z; acc[i][3] = bb.w; }
    }
#pragma unroll 4
    for (int j = 0; j < 64; ++j){
        float4 a = *(const float4*)&hT[j][e0];
        float4 b = *(const float4*)(ew2 + j * 64 + k0);
        fma16(acc, a, b);
    }
    // stash outputs for the segment-sum walk
#pragma unroll
    for (int i = 0; i < 4; ++i)
#pragma unroll
        for (int c = 0; c < 4; ++c)
            oS[e0 + i][k0 + c] = acc[i][c];
    // fused edge stats (raw outputs) -> sliced partials
    float ps[4], pq[4], pm[4];
#pragma unroll
    for (int c = 0; c < 4; ++c){
        float s0 = acc[0][c], s1 = acc[1][c], s2 = acc[2][c], s3 = acc[3][c];
        ps[c] = (s0 + s1) + (s2 + s3);
        pq[c] = fmaf(s0, s0, fmaf(s1, s1, fmaf(s2, s2, s3 * s3)));
        pm[c] = fmaxf(fmaxf(s0, s1), fmaxf(s2, s3));
    }
#pragma unroll
    for (int m = 1; m < 16; m <<= 1){
#pragma unroll
        for (int c = 0; c < 4; ++c){
            ps[c] += __shfl_xor(ps[c], m);
            pq[c] += __shfl_xor(pq[c], m);
            pm[c] = fmaxf(pm[c], __shfl_xor(pm[c], m));
        }
    }
    float* ep = epart + (size_t)(blockIdx.x & (NSLICE - 1)) * 192;
    if ((t & 15) == 0){
#pragma unroll
        for (int c = 0; c < 4; ++c){
            atomAddF(ep + k0 + c, ps[c]);
            atomAddF(ep + 64 + k0 + c, pq[c]);
            atomicMax((unsigned*)(ep + 128) + k0 + c, fkey(pm[c]));
        }
    }
    __syncthreads();
    // run-walk: senders are sorted within the block; all 64 lanes see the
    // same change points -> uniform branches. Interior runs own their node
    // exclusively -> plain store; boundary runs -> atomic.
    if (t < 64){
        int k = t;
        int cur = sArr[0];
        int jstart = 0;
        float a = 0.f;
        for (int j = 0; j < 64; ++j){
            int sj = sArr[j];
            if (sj != cur){
                float* dst = sent + (size_t)cur * 64 + k;
                if (jstart > 0) *dst = a; else atomAddF(dst, a);
                cur = sj; a = 0.f; jstart = j;
            }
            a += oS[j][k];
        }
        atomAddF(sent + (size_t)cur * 64 + k, a);   // touches block end
    }
}

// ---------------- edge MLP, fallback: atomic scatter ----------------
__global__ __launch_bounds__(256) void k_edge_atomic(const float* edges, const int* senders,
                                                     const float* nproj, const float* pre,
                                                     const float* ae, const float* ew2, const float* eb2,
                                                     float* sent, float* epart)
{
    __shared__ float hT[64][68];
    __shared__ int sArr[64];
    int t = threadIdx.x;
    int e = t & 63, kq = t >> 6;
    int eg = blockIdx.x * 64 + e;
    int s = senders[eg];
    if (kq == 0) sArr[e] = s;
    float pa = ae[0], pb = ae[1], pc = ae[2], pd = ae[3];
    const float* erow = edges + (size_t)eg * 3;
    float t0 = fmaf(pa, asinhf_fast(fmaf(pb, erow[0], pc)), pd);
    float t1 = fmaf(pa, asinhf_fast(fmaf(pb, erow[1], pc)), pd);
    float t2 = fmaf(pa, asinhf_fast(fmaf(pb, erow[2], pc)), pd);
    int j0 = kq * 16;
    const float* np = nproj + (size_t)s * 64 + j0;
    float npv[16];
#pragma unroll
    for (int q = 0; q < 4; ++q){
        float4 v = *(const float4*)(np + q * 4);
        npv[q * 4 + 0] = v.x; npv[q * 4 + 1] = v.y; npv[q * 4 + 2] = v.z; npv[q * 4 + 3] = v.w;
    }
    const float* Wc = pre + PRE_WC;
    const float* cvec = pre + PRE_CVEC;
#pragma unroll
    for (int jj = 0; jj < 16; ++jj){
        int j = j0 + jj;
        float hp = cvec[j] + npv[jj];
        hp = fmaf(t0, Wc[j], hp);
        hp = fmaf(t1, Wc[64 + j], hp);
        hp = fmaf(t2, Wc[128 + j], hp);
        hT[j][e] = gelu_f(hp);
    }
    __syncthreads();
    int e0 = (t & 15) * 4, k0 = (t >> 4) * 4;
    float acc[4][4];
    {
        float4 bb = *(const float4*)(eb2 + k0);
#pragma unroll
        for (int i = 0; i < 4; ++i){ acc[i][0] = bb.x; acc[i][1] = bb.y; acc[i][2] = bb.z; acc[i][3] = bb.w; }
    }
#pragma unroll 4
    for (int j = 0; j < 64; ++j){
        float4 a = *(const float4*)&hT[j][e0];
        float4 b = *(const float4*)(ew2 + j * 64 + k0);
        fma16(acc, a, b);
    }
#pragma unroll
    for (int i = 0; i < 4; ++i){
        int sv = sArr[e0 + i];
        float* dst = sent + (size_t)sv * 64 + k0;
        atomAddF(dst + 0, acc[i][0]);
        atomAddF(dst + 1, acc[i][1]);
        atomAddF(dst + 2, acc[i][2]);
        atomAddF(dst + 3, acc[i][3]);
    }
    float ps[4], pq[4], pm[4];
#pragma unroll
    for (int c = 0; c < 4; ++c){
        float s0 = acc[0][c], s1 = acc[1][c], s2 = acc[2][c], s3 = acc[3][c];
        ps[c] = (s0 + s1) + (s2 + s3);
        pq[c] = fmaf(s0, s0, fmaf(s1, s1, fmaf(s2, s2, s3 * s3)));
        pm[c] = fmaxf(fmaxf(s0, s1), fmaxf(s2, s3));
    }
#pragma unroll
    for (int m = 1; m < 16; m <<= 1){
#pragma unroll
        for (int c = 0; c < 4; ++c){
            ps[c] += __shfl_xor(ps[c], m);
            pq[c] += __shfl_xor(pq[c], m);
            pm[c] = fmaxf(pm[c], __shfl_xor(pm[c], m));
        }
    }
    float* ep = epart + (size_t)(blockIdx.x & (NSLICE - 1)) * 192;
    if ((t & 15) == 0){
#pragma unroll
        for (int c = 0; c < 4; ++c){
            atomAddF(ep + k0 + c, ps[c]);
            atomAddF(ep + 64 + k0 + c, pq[c]);
            atomicMax((unsigned*)(ep + 128) + k0 + c, fkey(pm[c]));
        }
    }
}

// ---------------- node MLP + node stats ----------------
__global__ __launch_bounds__(256) void k_node(const float* lat, const float* sent, const float* pre,
                                              const float* nw1, const float* nw2, const float* nb2,
                                              float* npart)
{
    __shared__ float ATl[64][68];
    __shared__ float ATs[64][68];
    __shared__ float h2T[64][68];
    int t = threadIdx.x;
    int base = blockIdx.x * 64;
    int cnt = NN - base; if (cnt > 64) cnt = 64;
#pragma unroll
    for (int it = 0; it < 4; ++it){
        int flat = it * 1024 + t * 4;
        int n = flat >> 6, j = flat & 63;
        float4 v = make_float4(0.f, 0.f, 0.f, 0.f);
        float4 w = make_float4(0.f, 0.f, 0.f, 0.f);
        if (n < cnt){
            v = *(const float4*)(lat + (size_t)(base + n) * 64 + j);
            w = *(const float4*)(sent + (size_t)(base + n) * 64 + j);
        }
        ATl[j + 0][n] = v.x; ATl[j + 1][n] = v.y; ATl[j + 2][n] = v.z; ATl[j + 3][n] = v.w;
        ATs[j + 0][n] = w.x; ATs[j + 1][n] = w.y; ATs[j + 2][n] = w.z; ATs[j + 3][n] = w.w;
    }
    __syncthreads();
    int e0 = (t & 15) * 4, k0 = (t >> 4) * 4;
    const float* Nsr = pre + PRE_NSR;
    float acc[4][4];
    {
        float4 g = *(const float4*)(pre + PRE_NGV + k0);
#pragma unroll
        for (int i = 0; i < 4; ++i){ acc[i][0] = g.x; acc[i][1] = g.y; acc[i][2] = g.z; acc[i][3] = g.w; }
    }
#pragma unroll 2
    for (int j = 0; j < 64; ++j){
        float4 a = *(const float4*)&ATl[j][e0];
        float4 b = *(const float4*)(nw1 + j * 64 + k0);
        fma16(acc, a, b);
        float4 a2 = *(const float4*)&ATs[j][e0];
        float4 b2 = *(const float4*)(Nsr + j * 64 + k0);
        fma16(acc, a2, b2);
    }
#pragma unroll
    for (int i = 0; i < 4; ++i)
#pragma unroll
        for (int c = 0; c < 4; ++c)
            h2T[k0 + c][e0 + i] = gelu_f(acc[i][c]);
    __syncthreads();
    float acc2[4][4];
    {
        float4 bb = *(const float4*)(nb2 + k0);
#pragma unroll
        for (int i = 0; i < 4; ++i){ acc2[i][0] = bb.x; acc2[i][1] = bb.y; acc2[i][2] = bb.z; acc2[i][3] = bb.w; }
    }
#pragma unroll 4
    for (int j = 0; j < 64; ++j){
        float4 a = *(const float4*)&h2T[j][e0];
        float4 b = *(const float4*)(nw2 + j * 64 + k0);
        fma16(acc2, a, b);
    }
    float ps[4] = {0.f, 0.f, 0.f, 0.f}, pq[4] = {0.f, 0.f, 0.f, 0.f}, pm[4];
#pragma unroll
    for (int c = 0; c < 4; ++c) pm[c] = -INFINITY;
#pragma unroll
    for (int i = 0; i < 4; ++i){
        if (e0 + i < cnt){
#pragma unroll
            for (int c = 0; c < 4; ++c){
                float v = acc2[i][c];
                ps[c] += v;
                pq[c] = fmaf(v, v, pq[c]);
                pm[c] = fmaxf(pm[c], v);
            }
        }
    }
#pragma unroll
    for (int m = 1; m < 16; m <<= 1){
#pragma unroll
        for (int c = 0; c < 4; ++c){
            ps[c] += __shfl_xor(ps[c], m);
            pq[c] += __shfl_xor(pq[c], m);
            pm[c] = fmaxf(pm[c], __shfl_xor(pm[c], m));
        }
    }
    float* np = npart + (size_t)(blockIdx.x & (NSLICE - 1)) * 192;
    if ((t & 15) == 0){
#pragma unroll
        for (int c = 0; c < 4; ++c){
            atomAddF(np + k0 + c, ps[c]);
            atomAddF(np + 64 + k0 + c, pq[c]);
            atomicMax((unsigned*)(np + 128) + k0 + c, fkey(pm[c]));
        }
    }
}

// ---------------- global head (1 block x 64) ----------------
__global__ void k_final(const float* pre, const float* epart, const float* npart,
                        const float* gw1, const float* gb1, const float* gw2, const float* gb2,
                        const float* gw3, const float* gb3, float* out)
{
    __shared__ float gin[576];
    __shared__ float l1s[64];
    __shared__ float l2s[64];
    int t = threadIdx.x;
    {
        float ns = 0.f, nq = 0.f; unsigned nmk = 0u;
        float es = 0.f, eq = 0.f; unsigned emk = 0u;
        for (int sl = 0; sl < NSLICE; ++sl){
            const float* np = npart + (size_t)sl * 192;
            const float* ep = epart + (size_t)sl * 192;
            ns += np[t]; nq += np[64 + t];
            unsigned a = ((const unsigned*)(np + 128))[t]; if (a > nmk) nmk = a;
            es += ep[t]; eq += ep[64 + t];
            unsigned b = ((const unsigned*)(ep + 128))[t]; if (b > emk) emk = b;
        }
        float mean = ns / 100000.0f;
        float var = nq / 100000.0f - mean * mean;
        gin[t] = asinhf_fast(ns);
        gin[64 + t] = asinhf_fast(mean);
        gin[128 + t] = asinhf_fast(var);
        gin[192 + t] = asinhf_fast(funkey(nmk));
        float meane = es / 1600000.0f;
        float vare = eq / 1600000.0f - meane * meane;
        gin[256 + t] = asinhf_fast(es);
        gin[320 + t] = asinhf_fast(meane);
        gin[384 + t] = asinhf_fast(vare);
        gin[448 + t] = asinhf_fast(funkey(emk));
        gin[512 + t] = pre[PRE_GLOB + t];
    }
    __syncthreads();
    float a1 = gb1[t];
    for (int j = 0; j < 576; ++j) a1 = fmaf(gin[j], gw1[j * 64 + t], a1);
    l1s[t] = gelu_f(a1);
    __syncthreads();
    float a2 = gb2[t];
    for (int j = 0; j < 64; ++j) a2 = fmaf(l1s[j], gw2[j * 64 + t], a2);
    l2s[t] = gelu_f(a2);
    __syncthreads();
    if (t < 2){
        float s = gb3[t];
        for (int j = 0; j < 64; ++j) s = fmaf(l2s[j], gw3[j * 2 + t], s);
        out[t] = s;
    }
}

extern "C" void kernel_launch(void* const* d_in, const int* in_sizes, int n_in,
                              void* d_out, int out_size, void* d_ws, size_t ws_size,
                              hipStream_t stream)
{
    const float* nodes  = (const float*)d_in[0];
    const float* edges  = (const float*)d_in[1];
    const int*   senders= (const int*)d_in[2];
    const float* an  = (const float*)d_in[3];
    const float* w_en= (const float*)d_in[4];
    const float* b_en= (const float*)d_in[5];
    const float* ae  = (const float*)d_in[6];
    const float* w_ee= (const float*)d_in[7];
    const float* b_ee= (const float*)d_in[8];
    const float* ag  = (const float*)d_in[9];
    const float* w_eg= (const float*)d_in[10];
    const float* b_eg= (const float*)d_in[11];
    const float* ew1 = (const float*)d_in[12];
    const float* eb1 = (const float*)d_in[13];
    const float* ew2 = (const float*)d_in[14];
    const float* eb2 = (const float*)d_in[15];
    const float* nw1 = (const float*)d_in[16];
    const float* nb1 = (const float*)d_in[17];
    const float* nw2 = (const float*)d_in[18];
    const float* nb2 = (const float*)d_in[19];
    const float* gw1 = (const float*)d_in[20];
    const float* gb1 = (const float*)d_in[21];
    const float* gw2 = (const float*)d_in[22];
    const float* gb2 = (const float*)d_in[23];
    const float* gw3 = (const float*)d_in[24];
    const float* gb3 = (const float*)d_in[25];

    char* ws = (char*)d_ws;
    float*  lat   = (float*)(ws);                       // 25.6 MB
    float*  nproj = (float*)(ws + 25600000);            // 25.6 MB
    float*  sent  = (float*)(ws + 51200000);            // 25.6 MB
    float*  pre   = (float*)(ws + 76800000);            // 34.6 KB used of 36 KB
    float*  epart = (float*)(ws + 76800000 + 36864);    // 16*192*4 = 12 KB
    float*  npart = (float*)(ws + 76800000 + 49152);    // 12 KB (region ends 76,865,536)
    int*    counts= (int*)  (ws + 77000000);            // 400 KB
    int*    cursor= (int*)  (ws + 77400000);            // 400 KB
    float4* eperm = (float4*)(ws + 77800000);           // 25.6 MB -> ends 103,400,000

    const size_t NEED_FAST = 103400000;
    bool fast = (ws_size >= NEED_FAST);

    hipMemsetAsync(sent, 0, (size_t)NN * 64 * sizeof(float), stream);
    hipMemsetAsync(epart, 0, 2 * NSLICE * 192 * sizeof(float), stream);  // epart+npart contiguous

    hipLaunchKernelGGL(k_pre, dim3(1), dim3(64), 0, stream,
                       an, w_en, b_en, ae, w_ee, b_ee, ag, w_eg, b_eg, ew1, eb1, nw1, nb1, pre);
    hipLaunchKernelGGL(k_embed, dim3(NN / 4), dim3(256), 0, stream, nodes, an, w_en, pre, lat);
    hipLaunchKernelGGL(k_nproj, dim3((NN + 63) / 64), dim3(256), 0, stream, lat, pre, nproj);

    if (fast){
        hipMemsetAsync(counts, 0, NN * sizeof(int), stream);
        hipLaunchKernelGGL(k_hist, dim3(NE / 256), dim3(256), 0, stream, senders, counts);
        hipLaunchKernelGGL(k_scan, dim3(1), dim3(1024), 0, stream, counts, cursor);
        hipLaunchKernelGGL(k_assign, dim3(NE / 256), dim3(256), 0, stream, edges, senders, cursor, eperm);
        hipLaunchKernelGGL(k_edge_sorted, dim3(NE / 64), dim3(256), 0, stream,
                           eperm, nproj, pre, ae, ew2, eb2, sent, epart);
    } else {
        hipLaunchKernelGGL(k_edge_atomic, dim3(NE / 64), dim3(256), 0, stream,
                           edges, senders, nproj, pre, ae, ew2, eb2, sent, epart);
    }

    hipLaunchKernelGGL(k_node, dim3((NN + 63) / 64), dim3(256), 0, stream,
                       lat, sent, pre, nw1, nw2, nb2, npart);
    hipLaunchKernelGGL(k_final, dim3(1), dim3(64), 0, stream,
                       pre, epart, npart, gw1, gb1, gw2, gb2, gw3, gb3, (float*)d_out);
}

// Round 3
// 704.595 us; speedup vs baseline: 5.7358x; 1.3796x over previous
//
#include <hip/hip_runtime.h>
#include <cstdint>
#include <cstddef>

#define NN 100000
#define NE 1600000
#define NSLICE 16

// pre-buffer layout (float offsets)
#define PRE_GLOB 0      // 64   glob_lat
#define PRE_WC   64     // 192  Wcomb (3x64): folded w_ee@ew1_edge
#define PRE_CVEC 256    // 64   eb1 + b_ee@ew1_edge + glob@ew1_glob
#define PRE_CN   320    // 64   b_en + t(0)*sum(w_en[0:4])
#define PRE_NGV  384    // 64   nb1 + glob@nw1_glob
#define PRE_WSR  448    // 4096 ew1_send+ew1_recv
#define PRE_NSR  4544   // 4096 nw1_send+nw1_recv

// preB tables (ushort offsets, each 8192): frag-layout bf16 hi/lo weights
// slot = tab*8192 + (((c*2+chunk)*2+part)*64 + lane)*8 + j
#define TAB_W2  0     // ew2
#define TAB_NW1 1     // nw1 rows 0..63
#define TAB_NSR 2     // nw1 send+recv sum
#define TAB_NW2 3     // nw2
#define TAB_WSR 4     // ew1 send+recv sum

typedef short v8s __attribute__((ext_vector_type(8)));
typedef float v4f __attribute__((ext_vector_type(4)));

__device__ __forceinline__ float asinhf_fast(float x){
    float ax = fabsf(x);
    float r = __logf(ax + sqrtf(fmaf(ax, ax, 1.0f)));
    return copysignf(r, x);
}
__device__ __forceinline__ float gelu_f(float x){
    float x3 = x * x * x;
    float z = 0.7978845608028654f * fmaf(0.044715f, x3, x);
    float e = __expf(2.0f * z);
    float th = 1.0f - 2.0f * __builtin_amdgcn_rcpf(e + 1.0f);
    return 0.5f * x * (1.0f + th);
}
__device__ __forceinline__ unsigned fkey(float f){
    unsigned u = __float_as_uint(f);
    return (u & 0x80000000u) ? ~u : (u | 0x80000000u);
}
__device__ __forceinline__ float funkey(unsigned k){
    unsigned u = (k & 0x80000000u) ? (k ^ 0x80000000u) : ~k;
    return __uint_as_float(u);
}
__device__ __forceinline__ void atomAddF(float* p, float v){
#if defined(__HIP_DEVICE_COMPILE__)
    unsafeAtomicAdd(p, v);
#else
    atomicAdd(p, v);
#endif
}
// RNE split of fp32 into bf16 hi + bf16 lo (hi+lo ~ 16-bit mantissa, zero-mean residual)
__device__ __forceinline__ void splitbf1(float x, unsigned short& h, unsigned short& l){
    unsigned u = __float_as_uint(x);
    unsigned hr = (u + 0x7FFFu + ((u >> 16) & 1u)) >> 16;
    h = (unsigned short)hr;
    float r = x - __uint_as_float(hr << 16);
    unsigned v = __float_as_uint(r);
    unsigned lr = (v + 0x7FFFu + ((v >> 16) & 1u)) >> 16;
    l = (unsigned short)lr;
}
__device__ __forceinline__ void split8(const float* x, v8s& hi, v8s& lo){
#pragma unroll
    for (int j = 0; j < 8; ++j){
        unsigned short h, l;
        splitbf1(x[j], h, l);
        hi[j] = (short)h; lo[j] = (short)l;
    }
}
__device__ __forceinline__ v4f mfma4(v8s ah, v8s al, v8s bh, v8s bl, v4f acc){
    acc = __builtin_amdgcn_mfma_f32_16x16x32_bf16(ah, bh, acc, 0, 0, 0);
    acc = __builtin_amdgcn_mfma_f32_16x16x32_bf16(ah, bl, acc, 0, 0, 0);
    acc = __builtin_amdgcn_mfma_f32_16x16x32_bf16(al, bh, acc, 0, 0, 0);
    acc = __builtin_amdgcn_mfma_f32_16x16x32_bf16(al, bl, acc, 0, 0, 0);
    return acc;
}
__device__ __forceinline__ void fma16(float acc[4][4], float4 a, float4 b){
    float av[4] = {a.x, a.y, a.z, a.w};
    float bv[4] = {b.x, b.y, b.z, b.w};
#pragma unroll
    for (int i = 0; i < 4; ++i)
#pragma unroll
        for (int c = 0; c < 4; ++c)
            acc[i][c] = fmaf(av[i], bv[c], acc[i][c]);
}

// ---------------- precompute (1 block x 256 threads) ----------------
__global__ __launch_bounds__(256) void k_pre(const float* an, const float* w_en, const float* b_en,
                      const float* ae, const float* w_ee, const float* b_ee,
                      const float* ag, const float* w_eg, const float* b_eg,
                      const float* ew1, const float* eb1,
                      const float* nw1, const float* nb1,
                      const float* ew2, const float* nw2,
                      float* pre, unsigned short* preB)
{
    __shared__ float gls[64];
    int t = threadIdx.x;
    if (t < 64){
        float g0 = asinhf_fast(100000.0f);
        float g1 = asinhf_fast(1600000.0f);
        float tg0 = fmaf(ag[0], asinhf_fast(fmaf(ag[1], g0, ag[2])), ag[3]);
        float tg1 = fmaf(ag[0], asinhf_fast(fmaf(ag[1], g1, ag[2])), ag[3]);
        float gl = fmaf(tg0, w_eg[t], fmaf(tg1, w_eg[64 + t], b_eg[t]));
        pre[PRE_GLOB + t] = gl;
        gls[t] = gl;
    }
    __syncthreads();
    if (t < 64){
        for (int i = 0; i < 3; ++i){
            float s = 0.f;
            for (int j = 0; j < 64; ++j) s = fmaf(w_ee[i * 64 + j], ew1[j * 64 + t], s);
            pre[PRE_WC + i * 64 + t] = s;
        }
        {
            float s = eb1[t];
            for (int j = 0; j < 64; ++j) s = fmaf(b_ee[j], ew1[j * 64 + t], s);
            for (int j = 0; j < 64; ++j) s = fmaf(gls[j], ew1[(192 + j) * 64 + t], s);
            pre[PRE_CVEC + t] = s;
        }
        {
            float tz = fmaf(an[0], asinhf_fast(an[2]), an[3]);
            pre[PRE_CN + t] = fmaf(tz, w_en[t] + w_en[64 + t] + w_en[128 + t] + w_en[192 + t], b_en[t]);
        }
        {
            float s = nb1[t];
            for (int j = 0; j < 64; ++j) s = fmaf(gls[j], nw1[(192 + j) * 64 + t], s);
            pre[PRE_NGV + t] = s;
        }
        for (int j = 0; j < 64; ++j){
            pre[PRE_WSR + j * 64 + t] = ew1[(64 + j) * 64 + t] + ew1[(128 + j) * 64 + t];
            pre[PRE_NSR + j * 64 + t] = nw1[(64 + j) * 64 + t] + nw1[(128 + j) * 64 + t];
        }
    }
    __syncthreads();
    // build frag-layout bf16 hi/lo tables
    const float* srcs[5] = {ew2, nw1, pre + PRE_NSR, nw2, pre + PRE_WSR};
    for (int idx = t; idx < 5 * 4096; idx += 256){
        int tab = idx >> 12;
        int rem = idx & 4095;
        int c = rem >> 10;
        int ch = (rem >> 9) & 1;
        int lane = (rem >> 3) & 63;
        int j = rem & 7;
        int k = ch * 32 + (lane >> 4) * 8 + j;
        int n = c * 16 + (lane & 15);
        float v = srcs[tab][k * 64 + n];
        unsigned short h, l;
        splitbf1(v, h, l);
        int base = tab * 8192 + ((c * 2 + ch) * 2) * 512 + lane * 8 + j;
        preB[base] = h;
        preB[base + 512] = l;
    }
}

// ---------------- fused embed + nproj (MFMA) ----------------
__global__ __launch_bounds__(256) void k_nproj(const float* nodes, const float* an,
                                               const float* w_en, const float* pre,
                                               const unsigned short* preB,
                                               float* lat, float* nproj)
{
    __shared__ float fz[64][4];
    __shared__ float latS[64][68];
    int t = threadIdx.x;
    int base = blockIdx.x * 64;
    int cnt = NN - base; if (cnt > 64) cnt = 64;
    if (t < 64){
        float pa = an[0], pb = an[1], pc = an[2], pd = an[3];
        int n = base + t;
        float t4 = 0.f, t5 = 0.f, t6 = 0.f;
        if (t < cnt){
            const float* row = nodes + (size_t)n * 7;
            t4 = fmaf(pa, asinhf_fast(fmaf(pb, row[4], pc)), pd);
            t5 = fmaf(pa, asinhf_fast(fmaf(pb, row[5], pc)), pd);
            t6 = fmaf(pa, asinhf_fast(fmaf(pb, row[6], pc)), pd);
        }
        fz[t][0] = t4; fz[t][1] = t5; fz[t][2] = t6;
    }
    __syncthreads();
    {
        int k = t & 63, grp = t >> 6;
        float w4 = w_en[4 * 64 + k], w5 = w_en[5 * 64 + k], w6 = w_en[6 * 64 + k];
        float cn = pre[PRE_CN + k];
#pragma unroll
        for (int i = 0; i < 16; ++i){
            int nl = grp * 16 + i;
            float v = 0.f;
            if (nl < cnt){
                v = cn;
                v = fmaf(fz[nl][0], w4, v);
                v = fmaf(fz[nl][1], w5, v);
                v = fmaf(fz[nl][2], w6, v);
                lat[(size_t)(base + nl) * 64 + k] = v;
            }
            latS[nl][k] = v;
        }
    }
    __syncthreads();
    int l = t & 63, w = t >> 6;
    int m = l & 15, q = l >> 4;
    // A-frags from latS
    v8s ah[2], al[2];
#pragma unroll
    for (int ch = 0; ch < 2; ++ch){
        float a[8];
        const float* src = &latS[w * 16 + m][ch * 32 + q * 8];
#pragma unroll
        for (int j = 0; j < 8; ++j) a[j] = src[j];
        split8(a, ah[ch], al[ch]);
    }
    const v8s* WB = (const v8s*)(preB + TAB_WSR * 8192);
    v4f acc[4];
#pragma unroll
    for (int c = 0; c < 4; ++c){
        acc[c] = (v4f){0.f, 0.f, 0.f, 0.f};
#pragma unroll
        for (int ch = 0; ch < 2; ++ch){
            v8s bh = WB[((c * 2 + ch) * 2 + 0) * 64 + l];
            v8s bl = WB[((c * 2 + ch) * 2 + 1) * 64 + l];
            acc[c] = mfma4(ah[ch], al[ch], bh, bl, acc[c]);
        }
    }
    // D: row = q*4+r (node-local in wave tile), col = c*16+m
#pragma unroll
    for (int c = 0; c < 4; ++c)
#pragma unroll
        for (int r = 0; r < 4; ++r){
            int nl = w * 16 + q * 4 + r;
            if (nl < cnt)
                nproj[(size_t)(base + nl) * 64 + c * 16 + m] = acc[c][r];
        }
}

// ---------------- counting sort: histogram ----------------
__global__ __launch_bounds__(256) void k_hist(const int* senders, int* counts)
{
    int i = blockIdx.x * 256 + threadIdx.x;
    atomicAdd(&counts[senders[i]], 1);
}

// ---------------- exclusive scan -> cursor (1 block x 1024) ----------------
__global__ __launch_bounds__(1024) void k_scan(const int* counts, int* cursor)
{
    __shared__ int part[1024];
    int t = threadIdx.x;
    const int CH = (NN + 1023) / 1024;
    int beg = t * CH; if (beg > NN) beg = NN;
    int end = beg + CH; if (end > NN) end = NN;
    int s = 0;
    for (int i = beg; i < end; ++i) s += counts[i];
    part[t] = s;
    __syncthreads();
    for (int off = 1; off < 1024; off <<= 1){
        int v = (t >= off) ? part[t - off] : 0;
        __syncthreads();
        if (t >= off) part[t] += v;
        __syncthreads();
    }
    int pref = (t == 0) ? 0 : part[t - 1];
    for (int i = beg; i < end; ++i){ cursor[i] = pref; pref += counts[i]; }
}

// ---------------- permute edge inputs into CSR order ----------------
__global__ __launch_bounds__(256) void k_assign(const float* edges, const int* senders,
                                                int* cursor, float4* eperm)
{
    int i = blockIdx.x * 256 + threadIdx.x;
    int s = senders[i];
    int slot = atomicAdd(&cursor[s], 1);
    const float* er = edges + (size_t)i * 3;
    eperm[slot] = make_float4(er[0], er[1], er[2], __int_as_float(s));
}

// ---------------- edge MLP (MFMA), sorted: per-block segment sum ----------------
__global__ __launch_bounds__(256) void k_edge_sorted(const float4* eperm, const float* nproj,
                                                     const float* pre, const unsigned short* preB,
                                                     const float* ae, const float* eb2,
                                                     float* sent, float* epart)
{
    __shared__ float oS[64][65];
    __shared__ float cWs[256];     // cvec[64] | Wc[192]
    __shared__ int sArr[64];
    __shared__ float sS[4][64], qS[4][64], mS[4][64];
    int t = threadIdx.x;
    cWs[t] = (t < 64) ? pre[PRE_CVEC + t] : pre[PRE_WC + t - 64];
    int l = t & 63, w = t >> 6;
    int m = l & 15, q = l >> 4;
    int e = w * 16 + m;                 // edge-local this lane computes (phase 1 / A-frag)
    float4 ed = eperm[blockIdx.x * 64 + e];
    int s = __float_as_int(ed.w);
    if (q == 0) sArr[e] = s;
    float pa = ae[0], pb = ae[1], pc = ae[2], pd = ae[3];
    float t0 = fmaf(pa, asinhf_fast(fmaf(pb, ed.x, pc)), pd);
    float t1 = fmaf(pa, asinhf_fast(fmaf(pb, ed.y, pc)), pd);
    float t2 = fmaf(pa, asinhf_fast(fmaf(pb, ed.z, pc)), pd);
    __syncthreads();
    // phase 1: this lane computes H[e][k] for k = ch*32 + q*8 + j  (its A-frag)
    v8s ah[2], al[2];
#pragma unroll
    for (int ch = 0; ch < 2; ++ch){
        int k0 = ch * 32 + q * 8;
        float cv[8], w0[8], w1[8], w2[8], np[8], h[8];
        const float* npp = nproj + (size_t)s * 64 + k0;
#pragma unroll
        for (int j = 0; j < 8; ++j){
            cv[j] = cWs[k0 + j];
            w0[j] = cWs[64 + k0 + j];
            w1[j] = cWs[128 + k0 + j];
            w2[j] = cWs[192 + k0 + j];
            np[j] = npp[j];
        }
#pragma unroll
        for (int j = 0; j < 8; ++j){
            float hp = cv[j] + np[j];
            hp = fmaf(t0, w0[j], hp);
            hp = fmaf(t1, w1[j], hp);
            hp = fmaf(t2, w2[j], hp);
            h[j] = gelu_f(hp);
        }
        split8(h, ah[ch], al[ch]);
    }
    // layer 2 via MFMA
    const v8s* WB = (const v8s*)(preB + TAB_W2 * 8192);
    v4f acc[4];
#pragma unroll
    for (int c = 0; c < 4; ++c){
        acc[c] = (v4f){0.f, 0.f, 0.f, 0.f};
#pragma unroll
        for (int ch = 0; ch < 2; ++ch){
            v8s bh = WB[((c * 2 + ch) * 2 + 0) * 64 + l];
            v8s bl = WB[((c * 2 + ch) * 2 + 1) * 64 + l];
            acc[c] = mfma4(ah[ch], al[ch], bh, bl, acc[c]);
        }
        float bb = eb2[c * 16 + m];
#pragma unroll
        for (int r = 0; r < 4; ++r) acc[c][r] += bb;
    }
    // stash D in LDS for the run-walk; D row = w*16 + q*4 + r, col = c*16+m
#pragma unroll
    for (int c = 0; c < 4; ++c)
#pragma unroll
        for (int r = 0; r < 4; ++r)
            oS[w * 16 + q * 4 + r][c * 16 + m] = acc[c][r];
    // stats: per-col partials over this wave's 16 edges
    float ps[4], pq[4], pm[4];
#pragma unroll
    for (int c = 0; c < 4; ++c){
        float s0 = acc[c][0], s1 = acc[c][1], s2 = acc[c][2], s3 = acc[c][3];
        ps[c] = (s0 + s1) + (s2 + s3);
        pq[c] = fmaf(s0, s0, fmaf(s1, s1, fmaf(s2, s2, s3 * s3)));
        pm[c] = fmaxf(fmaxf(s0, s1), fmaxf(s2, s3));
    }
#pragma unroll
    for (int msk = 16; msk <= 32; msk <<= 1){
#pragma unroll
        for (int c = 0; c < 4; ++c){
            ps[c] += __shfl_xor(ps[c], msk);
            pq[c] += __shfl_xor(pq[c], msk);
            pm[c] = fmaxf(pm[c], __shfl_xor(pm[c], msk));
        }
    }
    if (l < 16){
#pragma unroll
        for (int c = 0; c < 4; ++c){
            sS[w][c * 16 + l] = ps[c];
            qS[w][c * 16 + l] = pq[c];
            mS[w][c * 16 + l] = pm[c];
        }
    }
    __syncthreads();
    if (t < 64){
        // run-walk segment sum: senders sorted within block
        int k = t;
        int cur = sArr[0];
        int jstart = 0;
        float a = 0.f;
        for (int j = 0; j < 64; ++j){
            int sj = sArr[j];
            if (sj != cur){
                float* dst = sent + (size_t)cur * 64 + k;
                if (jstart > 0) *dst = a; else atomAddF(dst, a);
                cur = sj; a = 0.f; jstart = j;
            }
            a += oS[j][k];
        }
        atomAddF(sent + (size_t)cur * 64 + k, a);
    } else if (t < 128){
        int k = t - 64;
        float ssum = sS[0][k] + sS[1][k] + sS[2][k] + sS[3][k];
        float qsum = qS[0][k] + qS[1][k] + qS[2][k] + qS[3][k];
        float mmax = fmaxf(fmaxf(mS[0][k], mS[1][k]), fmaxf(mS[2][k], mS[3][k]));
        float* ep = epart + (size_t)(blockIdx.x & (NSLICE - 1)) * 192;
        atomAddF(ep + k, ssum);
        atomAddF(ep + 64 + k, qsum);
        atomicMax((unsigned*)(ep + 128) + k, fkey(mmax));
    }
}

// ---------------- edge MLP, fallback: atomic scatter (fp32) ----------------
__global__ __launch_bounds__(256) void k_edge_atomic(const float* edges, const int* senders,
                                                     const float* nproj, const float* pre,
                                                     const float* ae, const float* ew2, const float* eb2,
                                                     float* sent, float* epart)
{
    __shared__ float hT[64][68];
    __shared__ int sArr[64];
    int t = threadIdx.x;
    int e = t & 63, kq = t >> 6;
    int eg = blockIdx.x * 64 + e;
    int s = senders[eg];
    if (kq == 0) sArr[e] = s;
    float pa = ae[0], pb = ae[1], pc = ae[2], pd = ae[3];
    const float* erow = edges + (size_t)eg * 3;
    float t0 = fmaf(pa, asinhf_fast(fmaf(pb, erow[0], pc)), pd);
    float t1 = fmaf(pa, asinhf_fast(fmaf(pb, erow[1], pc)), pd);
    float t2 = fmaf(pa, asinhf_fast(fmaf(pb, erow[2], pc)), pd);
    int j0 = kq * 16;
    const float* np = nproj + (size_t)s * 64 + j0;
    float npv[16];
#pragma unroll
    for (int qq = 0; qq < 4; ++qq){
        float4 v = *(const float4*)(np + qq * 4);
        npv[qq * 4 + 0] = v.x; npv[qq * 4 + 1] = v.y; npv[qq * 4 + 2] = v.z; npv[qq * 4 + 3] = v.w;
    }
    const float* Wc = pre + PRE_WC;
    const float* cvec = pre + PRE_CVEC;
#pragma unroll
    for (int jj = 0; jj < 16; ++jj){
        int j = j0 + jj;
        float hp = cvec[j] + npv[jj];
        hp = fmaf(t0, Wc[j], hp);
        hp = fmaf(t1, Wc[64 + j], hp);
        hp = fmaf(t2, Wc[128 + j], hp);
        hT[j][e] = gelu_f(hp);
    }
    __syncthreads();
    int e0 = (t & 15) * 4, k0 = (t >> 4) * 4;
    float acc[4][4];
    {
        float4 bb = *(const float4*)(eb2 + k0);
#pragma unroll
        for (int i = 0; i < 4; ++i){ acc[i][0] = bb.x; acc[i][1] = bb.y; acc[i][2] = bb.z; acc[i][3] = bb.w; }
    }
#pragma unroll 4
    for (int j = 0; j < 64; ++j){
        float4 a = *(const float4*)&hT[j][e0];
        float4 b = *(const float4*)(ew2 + j * 64 + k0);
        fma16(acc, a, b);
    }
#pragma unroll
    for (int i = 0; i < 4; ++i){
        int sv = sArr[e0 + i];
        float* dst = sent + (size_t)sv * 64 + k0;
        atomAddF(dst + 0, acc[i][0]);
        atomAddF(dst + 1, acc[i][1]);
        atomAddF(dst + 2, acc[i][2]);
        atomAddF(dst + 3, acc[i][3]);
    }
    float ps[4], pq[4], pm[4];
#pragma unroll
    for (int c = 0; c < 4; ++c){
        float s0 = acc[0][c], s1 = acc[1][c], s2 = acc[2][c], s3 = acc[3][c];
        ps[c] = (s0 + s1) + (s2 + s3);
        pq[c] = fmaf(s0, s0, fmaf(s1, s1, fmaf(s2, s2, s3 * s3)));
        pm[c] = fmaxf(fmaxf(s0, s1), fmaxf(s2, s3));
    }
#pragma unroll
    for (int msk = 1; msk < 16; msk <<= 1){
#pragma unroll
        for (int c = 0; c < 4; ++c){
            ps[c] += __shfl_xor(ps[c], msk);
            pq[c] += __shfl_xor(pq[c], msk);
            pm[c] = fmaxf(pm[c], __shfl_xor(pm[c], msk));
        }
    }
    float* ep = epart + (size_t)(blockIdx.x & (NSLICE - 1)) * 192;
    if ((t & 15) == 0){
#pragma unroll
        for (int c = 0; c < 4; ++c){
            atomAddF(ep + k0 + c, ps[c]);
            atomAddF(ep + 64 + k0 + c, pq[c]);
            atomicMax((unsigned*)(ep + 128) + k0 + c, fkey(pm[c]));
        }
    }
}

// ---------------- node MLP (MFMA) + node stats ----------------
__global__ __launch_bounds__(256) void k_node(const float* lat, const float* sent, const float* pre,
                                              const unsigned short* preB, const float* nb2,
                                              float* npart)
{
    __shared__ float h2S[64][68];
    __shared__ float sS[4][64], qS[4][64], mS[4][64];
    int t = threadIdx.x;
    int base = blockIdx.x * 64;
    int cnt = NN - base; if (cnt > 64) cnt = 64;
    int l = t & 63, w = t >> 6;
    int m = l & 15, q = l >> 4;
    int rowA = w * 16 + m;
    bool vA = rowA < cnt;
    // layer-1 A-frags direct from global (k-contiguous)
    v8s lh[2], ll[2], sh[2], sl[2];
#pragma unroll
    for (int ch = 0; ch < 2; ++ch){
        float a[8], b[8];
        if (vA){
            const float* pl = lat + (size_t)(base + rowA) * 64 + ch * 32 + q * 8;
            const float* psn = sent + (size_t)(base + rowA) * 64 + ch * 32 + q * 8;
#pragma unroll
            for (int j = 0; j < 8; ++j){ a[j] = pl[j]; b[j] = psn[j]; }
        } else {
#pragma unroll
            for (int j = 0; j < 8; ++j){ a[j] = 0.f; b[j] = 0.f; }
        }
        split8(a, lh[ch], ll[ch]);
        split8(b, sh[ch], sl[ch]);
    }
    const v8s* B1 = (const v8s*)(preB + TAB_NW1 * 8192);
    const v8s* BS = (const v8s*)(preB + TAB_NSR * 8192);
    v4f acc[4];
#pragma unroll
    for (int c = 0; c < 4; ++c){
        acc[c] = (v4f){0.f, 0.f, 0.f, 0.f};
#pragma unroll
        for (int ch = 0; ch < 2; ++ch){
            v8s bh = B1[((c * 2 + ch) * 2 + 0) * 64 + l];
            v8s bl = B1[((c * 2 + ch) * 2 + 1) * 64 + l];
            acc[c] = mfma4(lh[ch], ll[ch], bh, bl, acc[c]);
            v8s ch2 = BS[((c * 2 + ch) * 2 + 0) * 64 + l];
            v8s cl2 = BS[((c * 2 + ch) * 2 + 1) * 64 + l];
            acc[c] = mfma4(sh[ch], sl[ch], ch2, cl2, acc[c]);
        }
        float g = pre[PRE_NGV + c * 16 + m];
#pragma unroll
        for (int r = 0; r < 4; ++r)
            h2S[w * 16 + q * 4 + r][c * 16 + m] = gelu_f(acc[c][r] + g);
    }
    __syncthreads();
    // layer-2 A-frags from h2S
    v8s ah[2], al[2];
#pragma unroll
    for (int ch = 0; ch < 2; ++ch){
        float a[8];
        const float* src = &h2S[w * 16 + m][ch * 32 + q * 8];
#pragma unroll
        for (int j = 0; j < 8; ++j) a[j] = src[j];
        split8(a, ah[ch], al[ch]);
    }
    const v8s* B2 = (const v8s*)(preB + TAB_NW2 * 8192);
    float ps[4], pq[4], pm[4];
#pragma unroll
    for (int c = 0; c < 4; ++c){
        v4f a2 = (v4f){0.f, 0.f, 0.f, 0.f};
#pragma unroll
        for (int ch = 0; ch < 2; ++ch){
            v8s bh = B2[((c * 2 + ch) * 2 + 0) * 64 + l];
            v8s bl = B2[((c * 2 + ch) * 2 + 1) * 64 + l];
            a2 = mfma4(ah[ch], al[ch], bh, bl, a2);
        }
        float bb = nb2[c * 16 + m];
        ps[c] = 0.f; pq[c] = 0.f; pm[c] = -INFINITY;
#pragma unroll
        for (int r = 0; r < 4; ++r){
            int nl = w * 16 + q * 4 + r;
            if (nl < cnt){
                float v = a2[r] + bb;
                ps[c] += v;
                pq[c] = fmaf(v, v, pq[c]);
                pm[c] = fmaxf(pm[c], v);
            }
        }
    }
#pragma unroll
    for (int msk = 16; msk <= 32; msk <<= 1){
#pragma unroll
        for (int c = 0; c < 4; ++c){
            ps[c] += __shfl_xor(ps[c], msk);
            pq[c] += __shfl_xor(pq[c], msk);
            pm[c] = fmaxf(pm[c], __shfl_xor(pm[c], msk));
        }
    }
    if (l < 16){
#pragma unroll
        for (int c = 0; c < 4; ++c){
            sS[w][c * 16 + l] = ps[c];
            qS[w][c * 16 + l] = pq[c];
            mS[w][c * 16 + l] = pm[c];
        }
    }
    __syncthreads();
    if (t < 64){
        int k = t;
        float ssum = sS[0][k] + sS[1][k] + sS[2][k] + sS[3][k];
        float qsum = qS[0][k] + qS[1][k] + qS[2][k] + qS[3][k];
        float mmax = fmaxf(fmaxf(mS[0][k], mS[1][k]), fmaxf(mS[2][k], mS[3][k]));
        float* np = npart + (size_t)(blockIdx.x & (NSLICE - 1)) * 192;
        atomAddF(np + k, ssum);
        atomAddF(np + 64 + k, qsum);
        atomicMax((unsigned*)(np + 128) + k, fkey(mmax));
    }
}

// ---------------- global head (1 block x 64) ----------------
__global__ void k_final(const float* pre, const float* epart, const float* npart,
                        const float* gw1, const float* gb1, const float* gw2, const float* gb2,
                        const float* gw3, const float* gb3, float* out)
{
    __shared__ float gin[576];
    __shared__ float l1s[64];
    __shared__ float l2s[64];
    int t = threadIdx.x;
    {
        float ns = 0.f, nq = 0.f; unsigned nmk = 0u;
        float es = 0.f, eq = 0.f; unsigned emk = 0u;
        for (int sl = 0; sl < NSLICE; ++sl){
            const float* np = npart + (size_t)sl * 192;
            const float* ep = epart + (size_t)sl * 192;
            ns += np[t]; nq += np[64 + t];
            unsigned a = ((const unsigned*)(np + 128))[t]; if (a > nmk) nmk = a;
            es += ep[t]; eq += ep[64 + t];
            unsigned b = ((const unsigned*)(ep + 128))[t]; if (b > emk) emk = b;
        }
        float mean = ns / 100000.0f;
        float var = nq / 100000.0f - mean * mean;
        gin[t] = asinhf_fast(ns);
        gin[64 + t] = asinhf_fast(mean);
        gin[128 + t] = asinhf_fast(var);
        gin[192 + t] = asinhf_fast(funkey(nmk));
        float meane = es / 1600000.0f;
        float vare = eq / 1600000.0f - meane * meane;
        gin[256 + t] = asinhf_fast(es);
        gin[320 + t] = asinhf_fast(meane);
        gin[384 + t] = asinhf_fast(vare);
        gin[448 + t] = asinhf_fast(funkey(emk));
        gin[512 + t] = pre[PRE_GLOB + t];
    }
    __syncthreads();
    float a1 = gb1[t];
    for (int j = 0; j < 576; ++j) a1 = fmaf(gin[j], gw1[j * 64 + t], a1);
    l1s[t] = gelu_f(a1);
    __syncthreads();
    float a2 = gb2[t];
    for (int j = 0; j < 64; ++j) a2 = fmaf(l1s[j], gw2[j * 64 + t], a2);
    l2s[t] = gelu_f(a2);
    __syncthreads();
    if (t < 2){
        float s = gb3[t];
        for (int j = 0; j < 64; ++j) s = fmaf(l2s[j], gw3[j * 2 + t], s);
        out[t] = s;
    }
}

extern "C" void kernel_launch(void* const* d_in, const int* in_sizes, int n_in,
                              void* d_out, int out_size, void* d_ws, size_t ws_size,
                              hipStream_t stream)
{
    const float* nodes  = (const float*)d_in[0];
    const float* edges  = (const float*)d_in[1];
    const int*   senders= (const int*)d_in[2];
    const float* an  = (const float*)d_in[3];
    const float* w_en= (const float*)d_in[4];
    const float* b_en= (const float*)d_in[5];
    const float* ae  = (const float*)d_in[6];
    const float* w_ee= (const float*)d_in[7];
    const float* b_ee= (const float*)d_in[8];
    const float* ag  = (const float*)d_in[9];
    const float* w_eg= (const float*)d_in[10];
    const float* b_eg= (const float*)d_in[11];
    const float* ew1 = (const float*)d_in[12];
    const float* eb1 = (const float*)d_in[13];
    const float* ew2 = (const float*)d_in[14];
    const float* eb2 = (const float*)d_in[15];
    const float* nw1 = (const float*)d_in[16];
    const float* nb1 = (const float*)d_in[17];
    const float* nw2 = (const float*)d_in[18];
    const float* nb2 = (const float*)d_in[19];
    const float* gw1 = (const float*)d_in[20];
    const float* gb1 = (const float*)d_in[21];
    const float* gw2 = (const float*)d_in[22];
    const float* gb2 = (const float*)d_in[23];
    const float* gw3 = (const float*)d_in[24];
    const float* gb3 = (const float*)d_in[25];

    char* ws = (char*)d_ws;
    float*  lat   = (float*)(ws);                         // 25.6 MB
    float*  nproj = (float*)(ws + 25600000);              // 25.6 MB
    float*  sent  = (float*)(ws + 51200000);              // 25.6 MB
    float*  pre   = (float*)(ws + 76800000);              // 64 KB reserved
    unsigned short* preB = (unsigned short*)(ws + 76865536); // 96 KB reserved (80 KB used)
    float*  epart = (float*)(ws + 76963840);              // 12 KB
    float*  npart = (float*)(ws + 76976128);              // 12 KB
    int*    counts= (int*)  (ws + 77000000);              // 400 KB
    int*    cursor= (int*)  (ws + 77400000);              // 400 KB
    float4* eperm = (float4*)(ws + 77800000);             // 25.6 MB -> ends 103,400,000

    const size_t NEED_FAST = 103400000;
    bool fast = (ws_size >= NEED_FAST);

    hipMemsetAsync(sent, 0, (size_t)NN * 64 * sizeof(float), stream);
    hipMemsetAsync(epart, 0, 2 * NSLICE * 192 * sizeof(float), stream);

    hipLaunchKernelGGL(k_pre, dim3(1), dim3(256), 0, stream,
                       an, w_en, b_en, ae, w_ee, b_ee, ag, w_eg, b_eg, ew1, eb1,
                       nw1, nb1, ew2, nw2, pre, preB);
    hipLaunchKernelGGL(k_nproj, dim3((NN + 63) / 64), dim3(256), 0, stream,
                       nodes, an, w_en, pre, preB, lat, nproj);

    if (fast){
        hipMemsetAsync(counts, 0, NN * sizeof(int), stream);
        hipLaunchKernelGGL(k_hist, dim3(NE / 256), dim3(256), 0, stream, senders, counts);
        hipLaunchKernelGGL(k_scan, dim3(1), dim3(1024), 0, stream, counts, cursor);
        hipLaunchKernelGGL(k_assign, dim3(NE / 256), dim3(256), 0, stream, edges, senders, cursor, eperm);
        hipLaunchKernelGGL(k_edge_sorted, dim3(NE / 64), dim3(256), 0, stream,
                           eperm, nproj, pre, preB, ae, eb2, sent, epart);
    } else {
        hipLaunchKernelGGL(k_edge_atomic, dim3(NE / 64), dim3(256), 0, stream,
                           edges, senders, nproj, pre, ae, ew2, eb2, sent, epart);
    }

    hipLaunchKernelGGL(k_node, dim3((NN + 63) / 64), dim3(256), 0, stream,
                       lat, sent, pre, preB, nb2, npart);
    hipLaunchKernelGGL(k_final, dim3(1), dim3(64), 0, stream,
                       pre, epart, npart, gw1, gb1, gw2, gb2, gw3, gb3, (float*)d_out);
}